// Round 13
// baseline (577.739 us; speedup 1.0000x reference)
//
#include <hip/hip_runtime.h>
#include <hip/hip_bf16.h>
#include <math.h>

// ---------------------------------------------------------------------------
// Quantized CNN forward (bitwise-exact vs fp32 reference):
//   block_k: maxpool2( quant_act( conv3x3(x, quant_weight(wk)), ak ) )
//   then global max over HxW, then 1x1 conv (10x128).
// Sparse formulation (R7+, absmax 0.0): ternary weights ~96% zero; skipping
// all-zero work is bitwise-safe; per-co accumulation stays (ci asc, k asc).
//
// R13: R12's counters (VGPR_Count=56 with ~105 live values, VALUBusy 45% =
// 206K VALU cyc/SIMD vs ~44K useful) prove the compiler allocated acc[16][4]
// in AGPRs: every FMA becomes v_accvgpr_read + v_fmac + v_accvgpr_write (3x
// issue). Same signature as R2/R10. Fix: PIN the accumulators into arch VGPRs
// with empty inline-asm "+v" constraints (init, per-chunk, epilogue). The
// allocator then keeps them VGPR-resident (shuttling across pins would need
// explicit copies). 105 live < (256,4)'s 128-reg budget -> no spills.
// Everything else is byte-identical to R12 (single-variable experiment).
// ---------------------------------------------------------------------------

__global__ __launch_bounds__(64)
void prep_zero(unsigned* __restrict__ maxb) {
    if (threadIdx.x < 4) maxb[threadIdx.x] = 0u;
}

__global__ __launch_bounds__(256)
void prep_absmax(const float* __restrict__ w1, const float* __restrict__ w2,
                 const float* __restrict__ w3, const float* __restrict__ wc,
                 unsigned* __restrict__ maxb) {
    const float* srcs[4] = {w1, w2, w3, wc};
    const int    ns[4]   = {32*3*9, 64*32*9, 128*64*9, 10*128};
    const int t = blockIdx.y;
    const float* s = srcs[t];
    const int    N = ns[t];
    float m = 0.f;
    for (int i = blockIdx.x * 256 + threadIdx.x; i < N; i += 16 * 256)
        m = fmaxf(m, fabsf(s[i]));
    #pragma unroll
    for (int o = 32; o > 0; o >>= 1) m = fmaxf(m, __shfl_down(m, o));
    __shared__ float red[4];
    const int lane = threadIdx.x & 63, wid = threadIdx.x >> 6;
    if (lane == 0) red[wid] = m;
    __syncthreads();
    if (threadIdx.x == 0) {
        float mm = fmaxf(fmaxf(red[0], red[1]), fmaxf(red[2], red[3]));
        atomicMax(maxb + t, __float_as_uint(mm));  // |w|>=0: uint order == float order
    }
}

__global__ __launch_bounds__(256)
void prep_quant(const float* __restrict__ w1, const float* __restrict__ w2,
                const float* __restrict__ w3, const float* __restrict__ wc,
                const unsigned* __restrict__ maxb,
                float* __restrict__ q1, float* __restrict__ q2,
                float* __restrict__ q3, float* __restrict__ qc) {
    const float* srcs[4] = {w1, w2, w3, wc};
    float*       dsts[4] = {q1, q2, q3, qc};
    const int    ns[4]   = {32*3*9, 64*32*9, 128*64*9, 10*128};
    const int t = blockIdx.y;
    const float* s = srcs[t];
    float*       d = dsts[t];
    const int    N = ns[t];
    const float sc = fmaxf(__uint_as_float(maxb[t]), 1e-8f);  // qmax = 2^(2-1)-1 = 1
    for (int i = blockIdx.x * 256 + threadIdx.x; i < N; i += 16 * 256)
        d[i] = rintf(s[i] / sc) * sc;
}

// Build (a) 128-bit pair masks per (grp-of-16-co, ci-chunk-of-8): bit
// (ci_local*16 + c) set iff pair (co=grp*16+c, ci=chunk*8+ci_local) has any
// nonzero weight; (b) padded coef table cw: 12-float (16B-aligned) rows,
// row = ((grp*nchunk+chunk)*8 + ci_local)*16 + c, coefs k=0..8 then 3 zeros.
__global__ __launch_bounds__(256)
void build_masks(const float* __restrict__ qw, int Co, int CIN,
                 unsigned* __restrict__ masks, float* __restrict__ cw) {
    const int nchunk = (CIN + 7) / 8;
    const int ngrp = Co / 16;
    const int ndw = ngrp * nchunk * 4;
    const int t = threadIdx.x;
    for (int i = t; i < ndw; i += 256) {
        const int row = i >> 2, d = i & 3;
        const int grp = row / nchunk, ch = row - grp * nchunk;
        unsigned m = 0;
        for (int bit = 0; bit < 32; ++bit) {
            const int lin = d * 32 + bit;          // ci_local*16 + c
            const int cil = lin >> 4, c = lin & 15;
            const int ci = ch * 8 + cil, co = grp * 16 + c;
            if (ci < CIN) {
                bool nz = false;
                for (int k = 0; k < 9; ++k)
                    nz |= (qw[(co * CIN + ci) * 9 + k] != 0.f);
                if (nz) m |= (1u << bit);
            }
        }
        masks[i] = m;
    }
    const int npair = ngrp * nchunk * 8 * 16;
    for (int pidx = t; pidx < npair; pidx += 256) {
        const int c = pidx & 15, rest = pidx >> 4;
        const int cil = rest & 7, row2 = rest >> 3;
        const int grp = row2 / nchunk, ch = row2 - grp * nchunk;
        const int ci = ch * 8 + cil, co = grp * 16 + c;
        float* dst = cw + (size_t)pidx * 12;
        #pragma unroll
        for (int k = 0; k < 9; ++k)
            dst[k] = (ci < CIN) ? qw[(co * CIN + ci) * 9 + k] : 0.f;
        dst[9] = dst[10] = dst[11] = 0.f;
    }
}

// Sparse fused conv3x3(pad=1) + maxpool2 + quant_act.
// 16x16 threads over a 16x16 pooled tile (32x32 conv px, 34x34 input tile).
// ci staged in chunks of 8 (flat slots tid+256*s, conflict-free ds_writes).
// Per ci: dense 4x4 patch (8 ds_read_b64); per co: uniform bit-test guarding
// a straight-line 36-FMA body with scalar-loaded coefs. Accs pinned to VGPRs.
template<int CIN, int Co>
__global__ __launch_bounds__(256, 4)
void conv_sparse(const float* __restrict__ in, const unsigned* __restrict__ masks,
                 const float* __restrict__ cw,
                 const float* __restrict__ alpha_p, float* __restrict__ out,
                 int H, int W) {
    constexpr int NCHUNK = (CIN + 7) / 8;
    constexpr int CCH    = (CIN < 8) ? CIN : 8;
    constexpr int NGRP   = Co / 16;
    const int PH = H >> 1, PW = W >> 1;
    const int tx = threadIdx.x, ty = threadIdx.y;
    const int tid = ty * 16 + tx;
    const int b   = blockIdx.z / NGRP;
    const int grp = blockIdx.z % NGRP;
    const int px  = blockIdx.x * 16 + tx;
    const int py  = blockIdx.y * 16 + ty;
    const int ix0 = blockIdx.x * 32 - 1;
    const int iy0 = blockIdx.y * 32 - 1;

    __shared__ float tile[CCH * 1156];           // chunk-local [ci][34*34] flat
    const size_t HW = (size_t)H * W;
    const float* inB = in + (size_t)b * CIN * HW;

    // Flat staging slots hoisted once; -1 = zero-fill (pad / out of image).
    int sidx[5];
    #pragma unroll
    for (int s = 0; s < 5; ++s) {
        const int idx = tid + 256 * s;
        const int r = idx / 34, c = idx - r * 34;
        const int gy = iy0 + r, gx = ix0 + c;
        sidx[s] = (idx < 1156 && gy >= 0 && gy < H && gx >= 0 && gx < W)
                  ? (gy * W + gx) : -1;
    }

    float acc[16][4];
    #pragma unroll
    for (int c = 0; c < 16; ++c)
        #pragma unroll
        for (int q = 0; q < 4; ++q) acc[c][q] = 0.f;

    // Pin accumulators into arch VGPRs (defeats the AGPR-offload heuristic).
    #pragma unroll
    for (int c = 0; c < 16; ++c)
        asm("" : "+v"(acc[c][0]), "+v"(acc[c][1]),
                 "+v"(acc[c][2]), "+v"(acc[c][3]));

    const int base = (2 * ty) * 34 + 2 * tx;     // even -> b64-aligned reads

    #pragma unroll 1
    for (int chunk = 0; chunk < NCHUNK; ++chunk) {
        if (chunk) __syncthreads();               // protect previous compute
        const int ch0 = chunk * 8;
        #pragma unroll
        for (int ch = 0; ch < CCH; ++ch) {
            const float* inC = inB + (size_t)(ch0 + ch) * HW;
            #pragma unroll
            for (int s = 0; s < 5; ++s) {
                const int idx = tid + 256 * s;    // imm-offset ds_write
                if (s < 4 || idx < 1156) {
                    const int g = sidx[s];
                    float v = 0.f;
                    if (g >= 0) v = inC[g];
                    tile[ch * 1156 + idx] = v;
                }
            }
        }
        __syncthreads();

        // 128-bit pair mask for (grp, chunk) -> scalar regs.
        const unsigned* mp = masks + (size_t)(grp * NCHUNK + chunk) * 4;
        unsigned mvec[4];
        #pragma unroll
        for (int d = 0; d < 4; ++d)
            mvec[d] = __builtin_amdgcn_readfirstlane(mp[d]);

        const float* cwc = cw + (size_t)((grp * NCHUNK + chunk) * 8) * 16 * 12;

        #pragma unroll 1
        for (int cil = 0; cil < CCH; ++cil) {
            const unsigned m16 = (mvec[cil >> 1] >> ((cil & 1) * 16)) & 0xffffu;
            if (!m16) continue;

            // Dense 4x4 patch: all nine k-stencils for the 2x2 outputs.
            float p[4][4];
            const float* tb = tile + cil * 1156 + base;
            #pragma unroll
            for (int r = 0; r < 4; ++r) {
                const float2 a  = *(const float2*)&tb[r * 34];
                const float2 c2 = *(const float2*)&tb[r * 34 + 2];
                p[r][0] = a.x; p[r][1] = a.y; p[r][2] = c2.x; p[r][3] = c2.y;
            }

            const float* cwr = cwc + (size_t)cil * 16 * 12;
            #pragma unroll
            for (int c = 0; c < 16; ++c) {
                if (m16 & (1u << c)) {            // uniform s_bitcmp+s_cbranch
                    const float* wp = cwr + c * 12;   // 16B-aligned row
                    #pragma unroll
                    for (int k = 0; k < 9; ++k) {
                        const float w = wp[k];        // uniform -> s_load
                        acc[c][0] = fmaf(w, p[k/3    ][k%3    ], acc[c][0]);
                        acc[c][1] = fmaf(w, p[k/3    ][k%3 + 1], acc[c][1]);
                        acc[c][2] = fmaf(w, p[k/3 + 1][k%3    ], acc[c][2]);
                        acc[c][3] = fmaf(w, p[k/3 + 1][k%3 + 1], acc[c][3]);
                    }
                }
            }
        }

        // Re-pin once per chunk: keeps accs VGPR-resident across the loop.
        #pragma unroll
        for (int c = 0; c < 16; ++c)
            asm("" : "+v"(acc[c][0]), "+v"(acc[c][1]),
                     "+v"(acc[c][2]), "+v"(acc[c][3]));
    }

    if (py < PH && px < PW) {
        const float alpha = *alpha_p;
        const float scale = alpha / 3.0f;         // 2^ABITS - 1 = 3
        #pragma unroll
        for (int c = 0; c < 16; ++c) {
            const float m = fmaxf(fmaxf(acc[c][0], acc[c][1]),
                                  fmaxf(acc[c][2], acc[c][3]));
            const float y = fminf(fmaxf(m, 0.f), alpha);
            out[(((size_t)b * Co + grp * 16 + c) * PH + py) * PW + px] =
                rintf(y / scale) * scale;
        }
    }
}

// One wave per (channel, batch): global max over 28x28.
__global__ __launch_bounds__(64)
void gmax_kernel(const float* __restrict__ h3, float* __restrict__ g) {
    const int c = blockIdx.x, b = blockIdx.y;
    const float* p = h3 + ((size_t)b * 128 + c) * 784;
    float m = -INFINITY;
    for (int i = threadIdx.x; i < 784; i += 64) m = fmaxf(m, p[i]);
    #pragma unroll
    for (int o = 32; o > 0; o >>= 1) m = fmaxf(m, __shfl_down(m, o));
    if (threadIdx.x == 0) g[b * 128 + c] = m;
}

// 1x1 conv 128->10 per batch (same k-ascending FMA order as round 1).
__global__ __launch_bounds__(128)
void classify_kernel(const float* __restrict__ g, const float* __restrict__ qwc,
                     float* __restrict__ out) {
    const int b = blockIdx.x;
    __shared__ float gg[128];
    gg[threadIdx.x] = g[b * 128 + threadIdx.x];
    __syncthreads();
    if (threadIdx.x < 10) {
        float s = 0.f;
        for (int k = 0; k < 128; ++k) s += qwc[threadIdx.x * 128 + k] * gg[k];
        out[b * 10 + threadIdx.x] = s;
    }
}

extern "C" void kernel_launch(void* const* d_in, const int* in_sizes, int n_in,
                              void* d_out, int out_size, void* d_ws, size_t ws_size,
                              hipStream_t stream) {
    const float* x  = (const float*)d_in[0];
    const float* w1 = (const float*)d_in[1];
    const float* w2 = (const float*)d_in[2];
    const float* w3 = (const float*)d_in[3];
    const float* wc = (const float*)d_in[4];
    const float* a1 = (const float*)d_in[5];
    const float* a2 = (const float*)d_in[6];
    const float* a3 = (const float*)d_in[7];

    float* ws = (float*)d_ws;
    size_t o = 0;
    float* qw1 = ws + o; o += 32 * 3 * 9;           // 864
    float* qw2 = ws + o; o += 64 * 32 * 9;          // 18432
    float* qw3 = ws + o; o += 128 * 64 * 9;         // 73728
    float* qwc = ws + o; o += 10 * 128;             // 1280
    unsigned* maxb = (unsigned*)(ws + o); o += 4;
    float* g   = ws + o; o += 32 * 128;             // 4096
    unsigned* mk1 = (unsigned*)(ws + o); o += 8;    // 2 grp * 1 ch * 4
    unsigned* mk2 = (unsigned*)(ws + o); o += 64;   // 4 grp * 4 ch * 4
    unsigned* mk3 = (unsigned*)(ws + o); o += 256;  // 8 grp * 8 ch * 4
    float* cw1 = ws + o; o += 2UL * 1 * 8 * 16 * 12;   //  3072 (16B aligned)
    float* cw2 = ws + o; o += 4UL * 4 * 8 * 16 * 12;   // 24576
    float* cw3 = ws + o; o += 8UL * 8 * 8 * 16 * 12;   // 98304
    float* h1p = ws + o; o += 32UL * 32 * 112 * 112;
    float* h2p = ws + o; o += 32UL * 64 * 56 * 56;
    float* h3p = ws + o; o += 32UL * 128 * 28 * 28;

    prep_zero<<<1, 64, 0, stream>>>(maxb);
    prep_absmax<<<dim3(16, 4), 256, 0, stream>>>(w1, w2, w3, wc, maxb);
    prep_quant<<<dim3(16, 4), 256, 0, stream>>>(w1, w2, w3, wc, maxb,
                                                qw1, qw2, qw3, qwc);
    build_masks<<<1, 256, 0, stream>>>(qw1, 32, 3,  mk1, cw1);
    build_masks<<<1, 256, 0, stream>>>(qw2, 64, 32, mk2, cw2);
    build_masks<<<1, 256, 0, stream>>>(qw3, 128, 64, mk3, cw3);

    // conv1: 3->32, 224x224 -> pooled 112x112. tiles 7x7, z = 32b * 2 grp
    conv_sparse<3, 32><<<dim3(7, 7, 32 * 2), dim3(16, 16), 0, stream>>>(
        x, mk1, cw1, a1, h1p, 224, 224);
    // conv2: 32->64, pooled 56x56. tiles 4x4, z = 32b * 4 grp
    conv_sparse<32, 64><<<dim3(4, 4, 32 * 4), dim3(16, 16), 0, stream>>>(
        h1p, mk2, cw2, a2, h2p, 112, 112);
    // conv3: 64->128, pooled 28x28. tiles 2x2, z = 32b * 8 grp
    conv_sparse<64, 128><<<dim3(2, 2, 32 * 8), dim3(16, 16), 0, stream>>>(
        h2p, mk3, cw3, a3, h3p, 56, 56);

    gmax_kernel<<<dim3(128, 32), 64, 0, stream>>>(h3p, g);
    classify_kernel<<<32, 128, 0, stream>>>(g, qwc, (float*)d_out);
}

// Round 14
// 477.739 us; speedup vs baseline: 1.2093x; 1.2093x over previous
//
#include <hip/hip_runtime.h>
#include <hip/hip_bf16.h>
#include <math.h>

// ---------------------------------------------------------------------------
// Quantized CNN forward (bitwise-exact vs fp32 reference):
//   block_k: maxpool2( quant_act( conv3x3(x, quant_weight(wk)), ak ) )
//   then global max over HxW, then 1x1 conv (10x128).
// Sparse formulation (R7+, absmax 0.0): ternary weights ~96% zero; skipping
// all-zero work is bitwise-safe; per-co accumulation stays (ci asc, k asc).
//
// R14: R13's null (VGPR pin changed nothing) kills the AGPR theory. Cycle
// accounting instead: conv2 = 456K cyc/CU for ~32 chunk-phases = 14K cyc per
// chunk vs ~2-3K issue work -> the wall is STAGING SERIALIZATION: per-element
// load->vmcnt->ds_write chains (the R5 dense kernel proved the fix: pipeline
// staging through registers so loads age a full compute phase before their
// ds_writes). This round: chunk=4 ci, in-flight buffer v[4][5] (20 regs);
// loads for chunk k+1 issued before compute(k), written after the barrier.
// Compute = R12's mask-guarded dense 36-FMA bodies, unchanged order.
// ---------------------------------------------------------------------------

__global__ __launch_bounds__(64)
void prep_zero(unsigned* __restrict__ maxb) {
    if (threadIdx.x < 4) maxb[threadIdx.x] = 0u;
}

__global__ __launch_bounds__(256)
void prep_absmax(const float* __restrict__ w1, const float* __restrict__ w2,
                 const float* __restrict__ w3, const float* __restrict__ wc,
                 unsigned* __restrict__ maxb) {
    const float* srcs[4] = {w1, w2, w3, wc};
    const int    ns[4]   = {32*3*9, 64*32*9, 128*64*9, 10*128};
    const int t = blockIdx.y;
    const float* s = srcs[t];
    const int    N = ns[t];
    float m = 0.f;
    for (int i = blockIdx.x * 256 + threadIdx.x; i < N; i += 16 * 256)
        m = fmaxf(m, fabsf(s[i]));
    #pragma unroll
    for (int o = 32; o > 0; o >>= 1) m = fmaxf(m, __shfl_down(m, o));
    __shared__ float red[4];
    const int lane = threadIdx.x & 63, wid = threadIdx.x >> 6;
    if (lane == 0) red[wid] = m;
    __syncthreads();
    if (threadIdx.x == 0) {
        float mm = fmaxf(fmaxf(red[0], red[1]), fmaxf(red[2], red[3]));
        atomicMax(maxb + t, __float_as_uint(mm));  // |w|>=0: uint order == float order
    }
}

__global__ __launch_bounds__(256)
void prep_quant(const float* __restrict__ w1, const float* __restrict__ w2,
                const float* __restrict__ w3, const float* __restrict__ wc,
                const unsigned* __restrict__ maxb,
                float* __restrict__ q1, float* __restrict__ q2,
                float* __restrict__ q3, float* __restrict__ qc) {
    const float* srcs[4] = {w1, w2, w3, wc};
    float*       dsts[4] = {q1, q2, q3, qc};
    const int    ns[4]   = {32*3*9, 64*32*9, 128*64*9, 10*128};
    const int t = blockIdx.y;
    const float* s = srcs[t];
    float*       d = dsts[t];
    const int    N = ns[t];
    const float sc = fmaxf(__uint_as_float(maxb[t]), 1e-8f);  // qmax = 2^(2-1)-1 = 1
    for (int i = blockIdx.x * 256 + threadIdx.x; i < N; i += 16 * 256)
        d[i] = rintf(s[i] / sc) * sc;
}

// Build (a) 64-bit pair masks per (grp-of-16-co, ci-chunk-of-4): bit
// (cil*16 + c) set iff pair (co=grp*16+c, ci=chunk*4+cil) has any nonzero
// weight; (b) padded coef table cw: 12-float (16B-aligned) rows,
// row = ((grp*nchunk+chunk)*4 + cil)*16 + c, coefs k=0..8 then 3 zeros.
__global__ __launch_bounds__(256)
void build_masks(const float* __restrict__ qw, int Co, int CIN,
                 unsigned* __restrict__ masks, float* __restrict__ cw) {
    const int nchunk = (CIN + 3) / 4;
    const int ngrp = Co / 16;
    const int ndw = ngrp * nchunk * 2;
    const int t = threadIdx.x;
    for (int i = t; i < ndw; i += 256) {
        const int row = i >> 1, d = i & 1;
        const int grp = row / nchunk, ch = row - grp * nchunk;
        unsigned m = 0;
        for (int bit = 0; bit < 32; ++bit) {
            const int lin = d * 32 + bit;          // cil*16 + c
            const int cil = lin >> 4, c = lin & 15;
            const int ci = ch * 4 + cil, co = grp * 16 + c;
            if (ci < CIN) {
                bool nz = false;
                for (int k = 0; k < 9; ++k)
                    nz |= (qw[(co * CIN + ci) * 9 + k] != 0.f);
                if (nz) m |= (1u << bit);
            }
        }
        masks[i] = m;
    }
    const int npair = ngrp * nchunk * 4 * 16;
    for (int pidx = t; pidx < npair; pidx += 256) {
        const int c = pidx & 15, rest = pidx >> 4;
        const int cil = rest & 3, row2 = rest >> 2;
        const int grp = row2 / nchunk, ch = row2 - grp * nchunk;
        const int ci = ch * 4 + cil, co = grp * 16 + c;
        float* dst = cw + (size_t)pidx * 12;
        #pragma unroll
        for (int k = 0; k < 9; ++k)
            dst[k] = (ci < CIN) ? qw[(co * CIN + ci) * 9 + k] : 0.f;
        dst[9] = dst[10] = dst[11] = 0.f;
    }
}

// Sparse fused conv3x3(pad=1) + maxpool2 + quant_act.
// 16x16 threads over a 16x16 pooled tile (32x32 conv px, 34x34 input tile).
// ci in chunks of 4; staging PIPELINED through registers: loads for chunk
// k+1 issue before compute(k), ds_writes consume them after the barrier.
// Per ci: dense 4x4 patch (8 ds_read_b64); per co: uniform bit-test guarding
// a straight-line 36-FMA body with scalar-loaded coefs.
template<int CIN, int Co>
__global__ __launch_bounds__(256, 4)
void conv_sparse(const float* __restrict__ in, const unsigned* __restrict__ masks,
                 const float* __restrict__ cw,
                 const float* __restrict__ alpha_p, float* __restrict__ out,
                 int H, int W) {
    constexpr int NCHUNK = (CIN + 3) / 4;
    constexpr int CCH    = (CIN < 4) ? CIN : 4;
    constexpr int NGRP   = Co / 16;
    const int PH = H >> 1, PW = W >> 1;
    const int tx = threadIdx.x, ty = threadIdx.y;
    const int tid = ty * 16 + tx;
    const int b   = blockIdx.z / NGRP;
    const int grp = blockIdx.z % NGRP;
    const int px  = blockIdx.x * 16 + tx;
    const int py  = blockIdx.y * 16 + ty;
    const int ix0 = blockIdx.x * 32 - 1;
    const int iy0 = blockIdx.y * 32 - 1;

    __shared__ float tile[CCH * 1156];           // chunk-local [cil][34*34] flat
    const size_t HW = (size_t)H * W;
    const float* inB = in + (size_t)b * CIN * HW;

    // Flat staging slots hoisted once; -1 = zero-fill (pad / out of image).
    int sidx[5];
    #pragma unroll
    for (int s = 0; s < 5; ++s) {
        const int idx = tid + 256 * s;
        const int r = idx / 34, c = idx - r * 34;
        const int gy = iy0 + r, gx = ix0 + c;
        sidx[s] = (idx < 1156 && gy >= 0 && gy < H && gx >= 0 && gx < W)
                  ? (gy * W + gx) : -1;
    }

    float v[CCH][5];                              // in-flight staging buffer
    auto load_chunk = [&](int ch0) {
        #pragma unroll
        for (int ch = 0; ch < CCH; ++ch) {
            const float* inC = inB + (size_t)(ch0 + ch) * HW;
            #pragma unroll
            for (int s = 0; s < 5; ++s)
                v[ch][s] = (sidx[s] >= 0) ? inC[sidx[s]] : 0.f;
        }
    };
    auto store_tile = [&]() {
        #pragma unroll
        for (int ch = 0; ch < CCH; ++ch)
            #pragma unroll
            for (int s = 0; s < 5; ++s) {
                const int idx = tid + 256 * s;    // imm-offset ds_write
                if (s < 4 || idx < 1156) tile[ch * 1156 + idx] = v[ch][s];
            }
    };

    float acc[16][4];
    #pragma unroll
    for (int c = 0; c < 16; ++c)
        #pragma unroll
        for (int q = 0; q < 4; ++q) acc[c][q] = 0.f;

    const int base = (2 * ty) * 34 + 2 * tx;     // even -> b64-aligned reads

    load_chunk(0);                                // prologue

    #pragma unroll 1
    for (int chunk = 0; chunk < NCHUNK; ++chunk) {
        __syncthreads();                          // tile free (prev compute done)
        store_tile();                             // v holds this chunk (aged)
        if (chunk + 1 < NCHUNK) load_chunk((chunk + 1) * 4);  // issue early
        __syncthreads();                          // writes visible

        // 64-bit pair mask for (grp, chunk) -> scalar regs.
        const unsigned* mp = masks + (size_t)(grp * NCHUNK + chunk) * 2;
        unsigned mvec[2];
        #pragma unroll
        for (int d = 0; d < 2; ++d)
            mvec[d] = __builtin_amdgcn_readfirstlane(mp[d]);

        const float* cwc = cw + (size_t)((grp * NCHUNK + chunk) * 4) * 16 * 12;

        #pragma unroll 1
        for (int cil = 0; cil < CCH; ++cil) {
            const unsigned m16 = (mvec[cil >> 1] >> ((cil & 1) * 16)) & 0xffffu;
            if (!m16) continue;

            // Dense 4x4 patch: all nine k-stencils for the 2x2 outputs.
            float p[4][4];
            const float* tb = tile + cil * 1156 + base;
            #pragma unroll
            for (int r = 0; r < 4; ++r) {
                const float2 a  = *(const float2*)&tb[r * 34];
                const float2 c2 = *(const float2*)&tb[r * 34 + 2];
                p[r][0] = a.x; p[r][1] = a.y; p[r][2] = c2.x; p[r][3] = c2.y;
            }

            const float* cwr = cwc + (size_t)cil * 16 * 12;
            #pragma unroll
            for (int c = 0; c < 16; ++c) {
                if (m16 & (1u << c)) {            // uniform s_bitcmp+s_cbranch
                    const float* wp = cwr + c * 12;   // 16B-aligned row
                    #pragma unroll
                    for (int k = 0; k < 9; ++k) {
                        const float w = wp[k];        // uniform -> s_load
                        acc[c][0] = fmaf(w, p[k/3    ][k%3    ], acc[c][0]);
                        acc[c][1] = fmaf(w, p[k/3    ][k%3 + 1], acc[c][1]);
                        acc[c][2] = fmaf(w, p[k/3 + 1][k%3    ], acc[c][2]);
                        acc[c][3] = fmaf(w, p[k/3 + 1][k%3 + 1], acc[c][3]);
                    }
                }
            }
        }
    }

    if (py < PH && px < PW) {
        const float alpha = *alpha_p;
        const float scale = alpha / 3.0f;         // 2^ABITS - 1 = 3
        #pragma unroll
        for (int c = 0; c < 16; ++c) {
            const float m = fmaxf(fmaxf(acc[c][0], acc[c][1]),
                                  fmaxf(acc[c][2], acc[c][3]));
            const float y = fminf(fmaxf(m, 0.f), alpha);
            out[(((size_t)b * Co + grp * 16 + c) * PH + py) * PW + px] =
                rintf(y / scale) * scale;
        }
    }
}

// One wave per (channel, batch): global max over 28x28.
__global__ __launch_bounds__(64)
void gmax_kernel(const float* __restrict__ h3, float* __restrict__ g) {
    const int c = blockIdx.x, b = blockIdx.y;
    const float* p = h3 + ((size_t)b * 128 + c) * 784;
    float m = -INFINITY;
    for (int i = threadIdx.x; i < 784; i += 64) m = fmaxf(m, p[i]);
    #pragma unroll
    for (int o = 32; o > 0; o >>= 1) m = fmaxf(m, __shfl_down(m, o));
    if (threadIdx.x == 0) g[b * 128 + c] = m;
}

// 1x1 conv 128->10 per batch (same k-ascending FMA order as round 1).
__global__ __launch_bounds__(128)
void classify_kernel(const float* __restrict__ g, const float* __restrict__ qwc,
                     float* __restrict__ out) {
    const int b = blockIdx.x;
    __shared__ float gg[128];
    gg[threadIdx.x] = g[b * 128 + threadIdx.x];
    __syncthreads();
    if (threadIdx.x < 10) {
        float s = 0.f;
        for (int k = 0; k < 128; ++k) s += qwc[threadIdx.x * 128 + k] * gg[k];
        out[b * 10 + threadIdx.x] = s;
    }
}

extern "C" void kernel_launch(void* const* d_in, const int* in_sizes, int n_in,
                              void* d_out, int out_size, void* d_ws, size_t ws_size,
                              hipStream_t stream) {
    const float* x  = (const float*)d_in[0];
    const float* w1 = (const float*)d_in[1];
    const float* w2 = (const float*)d_in[2];
    const float* w3 = (const float*)d_in[3];
    const float* wc = (const float*)d_in[4];
    const float* a1 = (const float*)d_in[5];
    const float* a2 = (const float*)d_in[6];
    const float* a3 = (const float*)d_in[7];

    float* ws = (float*)d_ws;
    size_t o = 0;
    float* qw1 = ws + o; o += 32 * 3 * 9;           // 864
    float* qw2 = ws + o; o += 64 * 32 * 9;          // 18432
    float* qw3 = ws + o; o += 128 * 64 * 9;         // 73728
    float* qwc = ws + o; o += 10 * 128;             // 1280
    unsigned* maxb = (unsigned*)(ws + o); o += 4;
    float* g   = ws + o; o += 32 * 128;             // 4096
    unsigned* mk1 = (unsigned*)(ws + o); o += 4;    // 2 grp * 1 ch * 2
    unsigned* mk2 = (unsigned*)(ws + o); o += 64;   // 4 grp * 8 ch * 2
    unsigned* mk3 = (unsigned*)(ws + o); o += 256;  // 8 grp * 16 ch * 2
    float* cw1 = ws + o; o += 2UL * 1 * 4 * 16 * 12;    //  1536 (16B aligned)
    float* cw2 = ws + o; o += 4UL * 8 * 4 * 16 * 12;    // 24576
    float* cw3 = ws + o; o += 8UL * 16 * 4 * 16 * 12;   // 98304
    float* h1p = ws + o; o += 32UL * 32 * 112 * 112;
    float* h2p = ws + o; o += 32UL * 64 * 56 * 56;
    float* h3p = ws + o; o += 32UL * 128 * 28 * 28;

    prep_zero<<<1, 64, 0, stream>>>(maxb);
    prep_absmax<<<dim3(16, 4), 256, 0, stream>>>(w1, w2, w3, wc, maxb);
    prep_quant<<<dim3(16, 4), 256, 0, stream>>>(w1, w2, w3, wc, maxb,
                                                qw1, qw2, qw3, qwc);
    build_masks<<<1, 256, 0, stream>>>(qw1, 32, 3,  mk1, cw1);
    build_masks<<<1, 256, 0, stream>>>(qw2, 64, 32, mk2, cw2);
    build_masks<<<1, 256, 0, stream>>>(qw3, 128, 64, mk3, cw3);

    // conv1: 3->32, 224x224 -> pooled 112x112. tiles 7x7, z = 32b * 2 grp
    conv_sparse<3, 32><<<dim3(7, 7, 32 * 2), dim3(16, 16), 0, stream>>>(
        x, mk1, cw1, a1, h1p, 224, 224);
    // conv2: 32->64, pooled 56x56. tiles 4x4, z = 32b * 4 grp
    conv_sparse<32, 64><<<dim3(4, 4, 32 * 4), dim3(16, 16), 0, stream>>>(
        h1p, mk2, cw2, a2, h2p, 112, 112);
    // conv3: 64->128, pooled 28x28. tiles 2x2, z = 32b * 8 grp
    conv_sparse<64, 128><<<dim3(2, 2, 32 * 8), dim3(16, 16), 0, stream>>>(
        h2p, mk3, cw3, a3, h3p, 56, 56);

    gmax_kernel<<<dim3(128, 32), 64, 0, stream>>>(h3p, g);
    classify_kernel<<<32, 128, 0, stream>>>(g, qwc, (float*)d_out);
}